// Round 13
// baseline (152.714 us; speedup 1.0000x reference)
//
#include <hip/hip_runtime.h>
#include <hip/hip_bf16.h>

// MHA forward, MI355X gfx950.
// cvt -> batched QKV proj GEMM (128x128 dbuf, counted vmcnt) -> causal flash
// attn (32x32x16 MFMA, in-register P via D-layout k-convention, 2-shuffle
// softmax, T13/T5/T14, XCD remap + LPT, 4 blk/CU) -> out GEMM.
// HIDDEN=1024, HEADS=16, HEAD_DIM=64, B=2, S=2048.

typedef __attribute__((ext_vector_type(4)))  float f32x4;
typedef __attribute__((ext_vector_type(16))) float f32x16;
typedef __attribute__((ext_vector_type(8)))  short bf16x8;
typedef unsigned short u16;

#define SEQ   2048
#define NH    16
#define HD    64
#define HID   1024
#define CEXP  0.1803368801f  // 0.125 * log2(e)
#define MEG   1048576u

#define BAR()    __builtin_amdgcn_s_barrier()
#define SCHED0() __builtin_amdgcn_sched_barrier(0)

static __device__ __forceinline__ u16 f2bf(float f) {
  union { __hip_bfloat16 h; u16 u; } c;
  c.h = __float2bfloat16(f);
  return c.u;
}

// XOR swizzle on 8-elem bf16 chunks within a 64-elem row (T2, G4).
static __device__ __forceinline__ int swz(int row, int col8) {
  return col8 ^ ((row & 7) << 3);
}

// async global->LDS, 16B/lane; lds dest wave-uniform base (guide §5).
static __device__ __forceinline__ void gll16(const void* g, void* l) {
  __builtin_amdgcn_global_load_lds(
      (const __attribute__((address_space(1))) void*)g,
      (__attribute__((address_space(3))) void*)l, 16, 0, 0);
}

// ---------------- f32 -> bf16 conversion: 16 x 1M-elem slices ----------------
__global__ __launch_bounds__(256) void cvt_kernel(
    const float* __restrict__ Wq, const float* __restrict__ Wk,
    const float* __restrict__ Wv, const float* __restrict__ Wo,
    const float* __restrict__ q, const float* __restrict__ k,
    const float* __restrict__ v,
    u16* __restrict__ wsout, u16* __restrict__ dob) {
  const int y = blockIdx.y;
  const int c = y & 3;
  const float* src;
  u16* dst;
  if (y < 4) {
    src = (y == 0) ? Wq : (y == 1) ? Wk : (y == 2) ? Wv : Wo;
    dst = wsout + (size_t)y * MEG;
  } else if (y < 8) {
    src = q + (size_t)c * MEG;
    dst = wsout + 4u * MEG + (size_t)c * MEG;
  } else if (y < 12) {
    src = k + (size_t)c * MEG;
    dst = dob + (size_t)c * MEG;
  } else {
    src = v + (size_t)c * MEG;
    dst = dob + 4u * MEG + (size_t)c * MEG;
  }
  int i = (blockIdx.x * 256 + threadIdx.x) * 4;
  float4 f = *(const float4*)(src + i);
  ushort4 o;
  o.x = f2bf(f.x); o.y = f2bf(f.y); o.z = f2bf(f.z); o.w = f2bf(f.w);
  *(ushort4*)(dst + i) = o;
}

// -------- batched QKV projection: C = X @ W^T + b, scatter to heads ----------
__global__ __launch_bounds__(256) void proj_kernel(
    const u16* __restrict__ Xq, const u16* __restrict__ Xk,
    const u16* __restrict__ Xv, const u16* __restrict__ Wc,
    const float* __restrict__ bq, const float* __restrict__ bk,
    const float* __restrict__ bvp,
    u16* __restrict__ Qo, u16* __restrict__ Ko, u16* __restrict__ Vto) {
  __shared__ u16 As[2][128 * 64];
  __shared__ u16 Bs[2][128 * 64];

  const int tid  = threadIdx.x;
  const int lane = tid & 63;
  const int wid  = tid >> 6;
  const int wm   = wid >> 1, wn = wid & 1;
  const int l15  = lane & 15;
  const int lhi  = lane >> 4;
  const int z    = blockIdx.z;
  const int bm   = blockIdx.x * 128;
  const int bn   = blockIdx.y * 128;

  const u16* X = (z == 0) ? Xq : (z == 1) ? Xk : Xv;
  const u16* W = Wc + (size_t)z * (HID * HID);
  const float* bias = (z == 0) ? bq : (z == 1) ? bk : bvp;

  f32x4 acc[4][4];
#pragma unroll
  for (int i = 0; i < 4; i++)
#pragma unroll
    for (int j = 0; j < 4; j++) acc[i][j] = (f32x4){0.f, 0.f, 0.f, 0.f};

  const int lrow  = lane >> 3;
  const int gcol8 = lane & 7;

#define PROJ_STAGE(buf, k0)                                                       \
  {                                                                               \
    _Pragma("unroll")                                                             \
    for (int c = 0; c < 4; c++) {                                                 \
      const int row  = c * 32 + wid * 8 + lrow;                                   \
      const int scol = (gcol8 ^ (row & 7)) * 8;                                   \
      gll16(X + (size_t)(bm + row) * HID + (k0) + scol,                           \
            (char*)&As[buf][0] + c * 4096 + wid * 1024);                          \
      gll16(W + (size_t)(bn + row) * HID + (k0) + scol,                           \
            (char*)&Bs[buf][0] + c * 4096 + wid * 1024);                          \
    }                                                                             \
  }

  PROJ_STAGE(0, 0);
  for (int t = 0; t < 16; t++) {
    BAR();
    if (t < 15) {
      PROJ_STAGE((t + 1) & 1, (t + 1) * 64);
      asm volatile("s_waitcnt vmcnt(8)" ::: "memory");
    } else {
      asm volatile("s_waitcnt vmcnt(0)" ::: "memory");
    }
    BAR();
    SCHED0();
    const u16* A = &As[t & 1][0];
    const u16* B = &Bs[t & 1][0];
#pragma unroll
    for (int ks = 0; ks < 2; ks++) {
      bf16x8 af[4], bfm[4];
#pragma unroll
      for (int i = 0; i < 4; i++) {
        const int row = wm * 64 + i * 16 + l15;
        af[i] = *(const bf16x8*)&A[row * 64 + swz(row, ks * 32 + lhi * 8)];
      }
#pragma unroll
      for (int j = 0; j < 4; j++) {
        const int row = wn * 64 + j * 16 + l15;
        bfm[j] = *(const bf16x8*)&B[row * 64 + swz(row, ks * 32 + lhi * 8)];
      }
#pragma unroll
      for (int i = 0; i < 4; i++)
#pragma unroll
        for (int j = 0; j < 4; j++)
          acc[i][j] = __builtin_amdgcn_mfma_f32_16x16x32_bf16(af[i], bfm[j], acc[i][j], 0, 0, 0);
    }
  }
#undef PROJ_STAGE

  const int bb = bm >> 11;
#pragma unroll
  for (int j = 0; j < 4; j++) {
    const int n = bn + wn * 64 + j * 16 + l15;
    const float bv_ = bias[n];
    const int h = n >> 6, d = n & 63;
    if (z == 2) {
#pragma unroll
      for (int i = 0; i < 4; i++) {
        const int s0 = (bm + wm * 64 + i * 16 + lhi * 4) & 2047;
        ushort4 t;
        t.x = f2bf(acc[i][j][0] + bv_);
        t.y = f2bf(acc[i][j][1] + bv_);
        t.z = f2bf(acc[i][j][2] + bv_);
        t.w = f2bf(acc[i][j][3] + bv_);
        *(ushort4*)&Vto[((size_t)(bb * NH + h) * HD + d) * SEQ + s0] = t;
      }
    } else {
      u16* O = z ? Ko : Qo;
#pragma unroll
      for (int i = 0; i < 4; i++)
#pragma unroll
        for (int r = 0; r < 4; r++) {
          const int m = bm + wm * 64 + i * 16 + lhi * 4 + r;
          const int s = m & 2047;
          O[(((size_t)(bb * NH + h) * SEQ + s) << 6) + d] = f2bf(acc[i][j][r] + bv_);
        }
    }
  }
}

// ---------------- causal flash attention (32x32x16 MFMA) ---------------------
// Q,K: bf16 [B,H,S,D]; Vt: bf16 [B,H,D,S]; out: bf16 [B,S,H*D].
// QBLK=128, 4 waves x 32 q-rows. Swapped QK^T: D col = q = lane&31, row k =
// (r&3)+8*(r>>2)+4g (HW-verified). PV A-operand = exp'd score regs directly
// (k-convention f(g,j)=4g+(j&3)+8(j>>2), consistent on A and B). 2 shuffles
// per softmax. K LDS [32][128] 8-chunk swz; V LDS [64][64] 4-granule swz.
__global__ __launch_bounds__(256, 4) void attn_kernel(
    const u16* __restrict__ Q, const u16* __restrict__ K,
    const u16* __restrict__ Vt, u16* __restrict__ Aout) {
  __shared__ __align__(16) char pool[16384];
  u16* Ksh = (u16*)pool;           // [32][128]
  u16* Vsh = (u16*)(pool + 8192);  // [64][64]

  const int tid  = threadIdx.x;
  const int lane = tid & 63;
  const int wid  = tid >> 6;       // 0..3, owns q-rows wid*32..+32
  const int l31  = lane & 31;
  const int g    = lane >> 5;

  // XCD remap (T1) + LPT (longest q-tiles first). 512 blocks.
  const int flat = blockIdx.x;
  const int slot = flat >> 3;
  const int bh   = (flat & 7) * 4 + (slot & 3);
  const int qt   = 15 - (slot >> 2);
  const int b    = bh >> 4, h = bh & 15;
  const size_t base = (size_t)bh * SEQ * HD;

  const int qrow = qt * 128 + wid * 32 + l31;  // this lane's q-row
  bf16x8 aq[4];
#pragma unroll
  for (int ds = 0; ds < 4; ds++)
    aq[ds] = *(const bf16x8*)&Q[base + (size_t)qrow * HD + ds * 16 + g * 8];

  f32x16 o[2];
#pragma unroll
  for (int r = 0; r < 16; r++) { o[0][r] = 0.f; o[1][r] = 0.f; }
  float m_s = -1e30f, l_s = 0.f;

  // staging: 256 threads cover one 64x64 tile per matrix (16 elems each)
  const int srow = tid >> 2;        // 0..63
  const int sd   = (tid & 3) * 16;
  const int krow = srow & 31;
  const int kcb  = ((srow >> 5) * 64 + sd) >> 3;   // K chunk base (0..15)
  u16* kdst0 = &Ksh[krow * 128 + (((kcb)     ^ (krow & 15)) << 3)];
  u16* kdst1 = &Ksh[krow * 128 + (((kcb + 1) ^ (krow & 15)) << 3)];
  const int vg0 = sd >> 2;                          // V granule base (0..15)

  union B2S { bf16x8 v; short4 s[2]; };
  B2S pk0, pk1, pv0, pv1;  // prefetched next-tile K/V (T14)

#define LOADR(kt_)                                                                \
  {                                                                               \
    const u16* kp = K + base + (size_t)((kt_) * 64 + srow) * HD + sd;             \
    pk0.v = *(const bf16x8*)kp;                                                   \
    pk1.v = *(const bf16x8*)(kp + 8);                                             \
    const u16* vp = Vt + base + (size_t)srow * SEQ + (kt_) * 64 + sd;             \
    pv0.v = *(const bf16x8*)vp;                                                   \
    pv1.v = *(const bf16x8*)(vp + 8);                                             \
  }

  LOADR(0);

  const int nkt = 2 * qt + 2;
  for (int kt = 0; kt < nkt; ++kt) {
    BAR();   // prior tile's LDS reads all consumed -> safe overwrite
    *(bf16x8*)kdst0 = pk0.v;
    *(bf16x8*)kdst1 = pk1.v;
#pragma unroll
    for (int i = 0; i < 4; i++) {
      short4 hv = (i < 2) ? pv0.s[i & 1] : pv1.s[i & 1];
      *(short4*)&Vsh[srow * 64 + (((vg0 + i) ^ (srow & 15)) << 2)] = hv;
    }
    if (kt + 1 < nkt) LOADR(kt + 1);  // stays in flight across compute
    asm volatile("s_waitcnt lgkmcnt(0)" ::: "memory");
    BAR();
    SCHED0();

    // ---- S^T = mfma(K, Q): sc[kb] covers k = kt*64 + kb*32 .. +32 ----
    f32x16 sc[2];
    __builtin_amdgcn_s_setprio(1);
#pragma unroll
    for (int kb = 0; kb < 2; kb++) {
#pragma unroll
      for (int r = 0; r < 16; r++) sc[kb][r] = 0.f;
#pragma unroll
      for (int ds = 0; ds < 4; ds++) {
        const int cc = kb * 8 + ds * 2 + g;
        bf16x8 kf = *(const bf16x8*)&Ksh[l31 * 128 + ((cc ^ (l31 & 15)) << 3)];
        sc[kb] = __builtin_amdgcn_mfma_f32_32x32x16_bf16(kf, aq[ds], sc[kb], 0, 0, 0);
      }
    }
    __builtin_amdgcn_s_setprio(0);

    if (kt >= 2 * qt) {  // causal mask (diagonal-adjacent tiles only)
#pragma unroll
      for (int kb = 0; kb < 2; kb++)
#pragma unroll
        for (int r = 0; r < 16; r++) {
          const int kg = kt * 64 + kb * 32 + (r & 3) + 8 * (r >> 2) + 4 * g;
          if (kg > qrow) sc[kb][r] = -1e30f;
        }
    }

    // ---- online softmax (2 shuffles), defer-max (T13) ----
    float mx = -1e30f;
#pragma unroll
    for (int kb = 0; kb < 2; kb++)
#pragma unroll
      for (int r = 0; r < 16; r++) mx = fmaxf(mx, sc[kb][r]);
    mx = fmaxf(mx, __shfl_xor(mx, 32, 64));
    if (__any(mx > m_s + 64.0f)) {  // raw-score THR (e^8 P-bound)
      const float mnew = fmaxf(m_s, mx);
      const float fac = __builtin_amdgcn_exp2f((m_s - mnew) * CEXP);
      l_s *= fac;
      m_s = mnew;
#pragma unroll
      for (int r = 0; r < 16; r++) {
        const float fr = __shfl(fac, (r & 3) + 8 * (r >> 2) + 4 * g, 64);
        o[0][r] *= fr;
        o[1][r] *= fr;
      }
    }
    const float nmc = -m_s * CEXP;
    float ps = 0.f;
#pragma unroll
    for (int kb = 0; kb < 2; kb++)
#pragma unroll
      for (int r = 0; r < 16; r++) {
        const float e = __builtin_amdgcn_exp2f(fmaf(sc[kb][r], CEXP, nmc));
        sc[kb][r] = e;
        ps += e;
      }
    ps += __shfl_xor(ps, 32, 64);
    l_s += ps;

    // ---- O += P V : A-frag slice s = bf16(sc[s>>1] regs 8*(s&1)..+7) ----
    __builtin_amdgcn_s_setprio(1);
#pragma unroll
    for (int s = 0; s < 4; s++) {
      const int kb = s >> 1, rb = (s & 1) * 8;
      bf16x8 pa;
#pragma unroll
      for (int j = 0; j < 8; j++) pa[j] = (short)f2bf(sc[kb][rb + j]);
#pragma unroll
      for (int dt = 0; dt < 2; dt++) {
        const int row = dt * 32 + l31;
        const int ga = ((4 * s + g)     ^ (row & 15)) << 2;
        const int gb = ((4 * s + g + 2) ^ (row & 15)) << 2;
        short4 b0 = *(const short4*)&Vsh[row * 64 + ga];
        short4 b1 = *(const short4*)&Vsh[row * 64 + gb];
        bf16x8 bv;
        bv[0] = b0.x; bv[1] = b0.y; bv[2] = b0.z; bv[3] = b0.w;
        bv[4] = b1.x; bv[5] = b1.y; bv[6] = b1.z; bv[7] = b1.w;
        o[dt] = __builtin_amdgcn_mfma_f32_32x32x16_bf16(pa, bv, o[dt], 0, 0, 0);
      }
    }
    __builtin_amdgcn_s_setprio(0);
  }
#undef LOADR

  // ---- normalize + store: o[dt][r] -> q=(r&3)+8(r>>2)+4g, d=dt*32+l31 ----
  float inv[16];
#pragma unroll
  for (int r = 0; r < 16; r++) {
    const float lr = __shfl(l_s, (r & 3) + 8 * (r >> 2) + 4 * g, 64);
    inv[r] = 1.0f / lr;
  }
#pragma unroll
  for (int dt = 0; dt < 2; dt++)
#pragma unroll
    for (int r = 0; r < 16; r++) {
      const int rowg = qt * 128 + wid * 32 + (r & 3) + 8 * (r >> 2) + 4 * g;
      Aout[(((size_t)(b * SEQ + rowg)) << 10) + h * 64 + dt * 32 + l31] =
          f2bf(o[dt][r] * inv[r]);
    }
}

// ---------------- out projection: f32 out = Ab @ Wo^T + bo -------------------
__global__ __launch_bounds__(256) void oproj_kernel(
    const u16* __restrict__ X, const u16* __restrict__ W,
    const float* __restrict__ bias, float* __restrict__ Out) {
  __shared__ u16 As[2][128 * 64];
  __shared__ u16 Bs[2][64 * 64];

  const int tid  = threadIdx.x;
  const int lane = tid & 63;
  const int wid  = tid >> 6;
  const int wm   = wid >> 1, wn = wid & 1;
  const int l15  = lane & 15;
  const int lhi  = lane >> 4;
  const int bm   = blockIdx.x * 128;
  const int bn   = blockIdx.y * 64;

  f32x4 acc[4][2];
#pragma unroll
  for (int i = 0; i < 4; i++)
#pragma unroll
    for (int j = 0; j < 2; j++) acc[i][j] = (f32x4){0.f, 0.f, 0.f, 0.f};

  const int lrow  = lane >> 3;
  const int gcol8 = lane & 7;

#define OPROJ_STAGE(buf, k0)                                                      \
  {                                                                               \
    _Pragma("unroll")                                                             \
    for (int c = 0; c < 4; c++) {                                                 \
      const int row  = c * 32 + wid * 8 + lrow;                                   \
      const int scol = (gcol8 ^ (row & 7)) * 8;                                   \
      gll16(X + (size_t)(bm + row) * HID + (k0) + scol,                           \
            (char*)&As[buf][0] + c * 4096 + wid * 1024);                          \
      if (c < 2)                                                                  \
        gll16(W + (size_t)(bn + row) * HID + (k0) + scol,                         \
              (char*)&Bs[buf][0] + c * 4096 + wid * 1024);                        \
    }                                                                             \
  }

  OPROJ_STAGE(0, 0);
  for (int t = 0; t < 16; t++) {
    BAR();
    if (t < 15) {
      OPROJ_STAGE((t + 1) & 1, (t + 1) * 64);
      asm volatile("s_waitcnt vmcnt(6)" ::: "memory");
    } else {
      asm volatile("s_waitcnt vmcnt(0)" ::: "memory");
    }
    BAR();
    SCHED0();
    const u16* A = &As[t & 1][0];
    const u16* B = &Bs[t & 1][0];
#pragma unroll
    for (int ks = 0; ks < 2; ks++) {
      bf16x8 af[4], bfm[2];
#pragma unroll
      for (int i = 0; i < 4; i++) {
        const int row = wm * 64 + i * 16 + l15;
        af[i] = *(const bf16x8*)&A[row * 64 + swz(row, ks * 32 + lhi * 8)];
      }
#pragma unroll
      for (int j = 0; j < 2; j++) {
        const int row = wn * 32 + j * 16 + l15;
        bfm[j] = *(const bf16x8*)&B[row * 64 + swz(row, ks * 32 + lhi * 8)];
      }
#pragma unroll
      for (int i = 0; i < 4; i++)
#pragma unroll
        for (int j = 0; j < 2; j++)
          acc[i][j] = __builtin_amdgcn_mfma_f32_16x16x32_bf16(af[i], bfm[j], acc[i][j], 0, 0, 0);
    }
  }
#undef OPROJ_STAGE

#pragma unroll
  for (int j = 0; j < 2; j++) {
    const int n = bn + wn * 32 + j * 16 + l15;
    const float bv_ = bias[n];
#pragma unroll
    for (int i = 0; i < 4; i++)
#pragma unroll
      for (int r = 0; r < 4; r++) {
        const int m = bm + wm * 64 + i * 16 + lhi * 4 + r;
        Out[(size_t)m * HID + n] = acc[i][j][r] + bv_;
      }
  }
}

// ---------------- launch ------------------------------------------------------
extern "C" void kernel_launch(void* const* d_in, const int* in_sizes, int n_in,
                              void* d_out, int out_size, void* d_ws, size_t ws_size,
                              hipStream_t stream) {
  const float* q  = (const float*)d_in[0];
  const float* k  = (const float*)d_in[1];
  const float* v  = (const float*)d_in[2];
  const float* Wq = (const float*)d_in[3];
  const float* bq = (const float*)d_in[4];
  const float* Wk = (const float*)d_in[5];
  const float* bk = (const float*)d_in[6];
  const float* Wv = (const float*)d_in[7];
  const float* bv = (const float*)d_in[8];
  const float* Wo = (const float*)d_in[9];
  const float* bo = (const float*)d_in[10];

  u16* ws   = (u16*)d_ws;
  u16* wqkv = ws;                     // Wq,Wk,Wv bf16 @ 0,1M,2M
  u16* wob  = ws + 3u * MEG;          // Wo bf16
  u16* qb   = ws + 4u * MEG;          // q bf16; reused as Ab after proj
  u16* Qb   = ws + 8u * MEG;          // [B,H,S,D]
  u16* Kb   = ws + 12u * MEG;         // [B,H,S,D]
  u16* Vtb  = ws + 16u * MEG;         // [B,H,D,S]
  u16* Ab   = qb;
  u16* kbf  = (u16*)d_out;            // k bf16 in d_out scratch
  u16* vbf  = (u16*)d_out + 4u * MEG; // v bf16

  cvt_kernel<<<dim3(1024, 16), 256, 0, stream>>>(Wq, Wk, Wv, Wo, q, k, v, ws, kbf);

  proj_kernel<<<dim3(32, 8, 3), 256, 0, stream>>>(qb, kbf, vbf, wqkv, bq, bk, bv,
                                                  Qb, Kb, Vtb);

  attn_kernel<<<dim3(512), 256, 0, stream>>>(Qb, Kb, Vtb, Ab);

  oproj_kernel<<<dim3(32, 16), 256, 0, stream>>>(Ab, wob, bo, (float*)d_out);
}

// Round 14
// 104.714 us; speedup vs baseline: 1.4584x; 1.4584x over previous
//
#include <hip/hip_runtime.h>
#include <hip/hip_bf16.h>

// MHA forward, MI355X gfx950.
// cvt (weights+activations -> bf16) -> batched QKV proj GEMM (128x64 dbuf,
// raw-barrier + counted vmcnt(6), 3 blk/CU) -> causal flash attn (R9-exact:
// 2 k-groups, swapped-QK softmax, T13/T5, true-T14, XCD remap + LPT)
// -> out GEMM (async dbuf).
// HIDDEN=1024, HEADS=16, HEAD_DIM=64, B=2, S=2048.

typedef __attribute__((ext_vector_type(4))) float f32x4;
typedef __attribute__((ext_vector_type(8))) short bf16x8;
typedef unsigned short u16;

#define SEQ   2048
#define NH    16
#define HD    64
#define HID   1024
#define CEXP  0.1803368801f  // 0.125 * log2(e)
#define MEG   1048576u

#define BAR()    __builtin_amdgcn_s_barrier()
#define SCHED0() __builtin_amdgcn_sched_barrier(0)

// HW round-to-nearest-even f32->bf16.
static __device__ __forceinline__ u16 f2bf(float f) {
  union { __hip_bfloat16 h; u16 u; } c;
  c.h = __float2bfloat16(f);
  return c.u;
}

// XOR swizzle on 8-elem bf16 chunks within a 64-elem row (T2, G4).
static __device__ __forceinline__ int swz(int row, int col8) {
  return col8 ^ ((row & 7) << 3);
}

// async global->LDS, 16B/lane; lds dest wave-uniform base (guide §5).
static __device__ __forceinline__ void gll16(const void* g, void* l) {
  __builtin_amdgcn_global_load_lds(
      (const __attribute__((address_space(1))) void*)g,
      (__attribute__((address_space(3))) void*)l, 16, 0, 0);
}

// ---------------- f32 -> bf16 conversion: 16 x 1M-elem slices ----------------
__global__ __launch_bounds__(256) void cvt_kernel(
    const float* __restrict__ Wq, const float* __restrict__ Wk,
    const float* __restrict__ Wv, const float* __restrict__ Wo,
    const float* __restrict__ q, const float* __restrict__ k,
    const float* __restrict__ v,
    u16* __restrict__ wsout, u16* __restrict__ dob) {
  const int y = blockIdx.y;
  const int c = y & 3;
  const float* src;
  u16* dst;
  if (y < 4) {
    src = (y == 0) ? Wq : (y == 1) ? Wk : (y == 2) ? Wv : Wo;
    dst = wsout + (size_t)y * MEG;
  } else if (y < 8) {
    src = q + (size_t)c * MEG;
    dst = wsout + 4u * MEG + (size_t)c * MEG;
  } else if (y < 12) {
    src = k + (size_t)c * MEG;
    dst = dob + (size_t)c * MEG;
  } else {
    src = v + (size_t)c * MEG;
    dst = dob + 4u * MEG + (size_t)c * MEG;
  }
  int i = (blockIdx.x * 256 + threadIdx.x) * 4;
  float4 f = *(const float4*)(src + i);
  ushort4 o;
  o.x = f2bf(f.x); o.y = f2bf(f.y); o.z = f2bf(f.z); o.w = f2bf(f.w);
  *(ushort4*)(dst + i) = o;
}

// -------- batched QKV projection: C = X @ W^T + b, scatter to heads ----------
// z=0: Q -> [B,H,S,D]; z=1: K -> [B,H,S,D]; z=2: V -> [B,H,D,S] (transposed).
// 128x64 tile, BK=64, async dbuf: raw s_barrier + counted vmcnt(6).
// 48 KB LDS -> 3 blocks/CU; grid (32,16,3) = 1536 blocks.
__global__ __launch_bounds__(256) void proj_kernel(
    const u16* __restrict__ Xq, const u16* __restrict__ Xk,
    const u16* __restrict__ Xv, const u16* __restrict__ Wc,
    const float* __restrict__ bq, const float* __restrict__ bk,
    const float* __restrict__ bvp,
    u16* __restrict__ Qo, u16* __restrict__ Ko, u16* __restrict__ Vto) {
  __shared__ u16 As[2][128 * 64];
  __shared__ u16 Bs[2][64 * 64];

  const int tid  = threadIdx.x;
  const int lane = tid & 63;
  const int wid  = tid >> 6;
  const int wm   = wid >> 1, wn = wid & 1;
  const int l15  = lane & 15;
  const int lhi  = lane >> 4;
  const int z    = blockIdx.z;
  const int bm   = blockIdx.x * 128;
  const int bn   = blockIdx.y * 64;

  const u16* X = (z == 0) ? Xq : (z == 1) ? Xk : Xv;
  const u16* W = Wc + (size_t)z * (HID * HID);
  const float* bias = (z == 0) ? bq : (z == 1) ? bk : bvp;

  f32x4 acc[4][2];
#pragma unroll
  for (int i = 0; i < 4; i++)
#pragma unroll
    for (int j = 0; j < 2; j++) acc[i][j] = (f32x4){0.f, 0.f, 0.f, 0.f};

  const int lrow  = lane >> 3;      // 0..7
  const int gcol8 = lane & 7;       // 8-elem chunk index

#define PROJ_STAGE(buf, k0)                                                       \
  {                                                                               \
    _Pragma("unroll")                                                             \
    for (int c = 0; c < 4; c++) {                                                 \
      const int row  = c * 32 + wid * 8 + lrow;                                   \
      const int scol = (gcol8 ^ (row & 7)) * 8; /* inverse-swizzled source */     \
      gll16(X + (size_t)(bm + row) * HID + (k0) + scol,                           \
            (char*)&As[buf][0] + c * 4096 + wid * 1024);                          \
      if (c < 2)                                                                  \
        gll16(W + (size_t)(bn + row) * HID + (k0) + scol,                         \
              (char*)&Bs[buf][0] + c * 4096 + wid * 1024);                        \
    }                                                                             \
  }

  PROJ_STAGE(0, 0);
  for (int t = 0; t < 16; t++) {
    BAR();  // prev compute done on all waves -> safe to overwrite buf[(t+1)&1]
    if (t < 15) {
      PROJ_STAGE((t + 1) & 1, (t + 1) * 64);
      asm volatile("s_waitcnt vmcnt(6)" ::: "memory");  // tile t landed; t+1 in flight
    } else {
      asm volatile("s_waitcnt vmcnt(0)" ::: "memory");
    }
    BAR();  // all waves' tile-t loads visible
    SCHED0();
    const u16* A = &As[t & 1][0];
    const u16* B = &Bs[t & 1][0];
#pragma unroll
    for (int ks = 0; ks < 2; ks++) {
      bf16x8 af[4], bfm[2];
#pragma unroll
      for (int i = 0; i < 4; i++) {
        const int row = wm * 64 + i * 16 + l15;
        af[i] = *(const bf16x8*)&A[row * 64 + swz(row, ks * 32 + lhi * 8)];
      }
#pragma unroll
      for (int j = 0; j < 2; j++) {
        const int row = wn * 32 + j * 16 + l15;
        bfm[j] = *(const bf16x8*)&B[row * 64 + swz(row, ks * 32 + lhi * 8)];
      }
#pragma unroll
      for (int i = 0; i < 4; i++)
#pragma unroll
        for (int j = 0; j < 2; j++)
          acc[i][j] = __builtin_amdgcn_mfma_f32_16x16x32_bf16(af[i], bfm[j], acc[i][j], 0, 0, 0);
    }
  }
#undef PROJ_STAGE

  // epilogue: bias + scatter to heads
  const int bb = bm >> 11;  // tile never crosses batch
#pragma unroll
  for (int j = 0; j < 2; j++) {
    const int n = bn + wn * 32 + j * 16 + l15;
    const float bv_ = bias[n];
    const int h = n >> 6, d = n & 63;
    if (z == 2) {
#pragma unroll
      for (int i = 0; i < 4; i++) {
        const int s0 = (bm + wm * 64 + i * 16 + lhi * 4) & 2047;
        ushort4 t;
        t.x = f2bf(acc[i][j][0] + bv_);
        t.y = f2bf(acc[i][j][1] + bv_);
        t.z = f2bf(acc[i][j][2] + bv_);
        t.w = f2bf(acc[i][j][3] + bv_);
        *(ushort4*)&Vto[((size_t)(bb * NH + h) * HD + d) * SEQ + s0] = t;
      }
    } else {
      u16* O = z ? Ko : Qo;
#pragma unroll
      for (int i = 0; i < 4; i++)
#pragma unroll
        for (int r = 0; r < 4; r++) {
          const int m = bm + wm * 64 + i * 16 + lhi * 4 + r;
          const int s = m & 2047;
          O[(((size_t)(bb * NH + h) * SEQ + s) << 6) + d] = f2bf(acc[i][j][r] + bv_);
        }
    }
  }
}

// ---------------- causal flash attention (R9-exact) --------------------------
// Q,K: bf16 [B,H,S,D]; Vt: bf16 [B,H,D,S]; out: bf16 [B,S,H*D].
// 512 thr = 2 k-groups x 4 row-waves; swapped QK^T (lane = one q-row).
// True T14: barrier-2 drains lgkm only, global reg-prefetch stays in flight.
__global__ __launch_bounds__(512) void attn_kernel(
    const u16* __restrict__ Q, const u16* __restrict__ K,
    const u16* __restrict__ Vt, u16* __restrict__ Aout) {
  __shared__ __align__(16) char pool[51200];

  const int tid  = threadIdx.x;
  const int lane = tid & 63;
  const int wid  = tid >> 6;
  const int rw   = wid & 3;
  const int g    = wid >> 2;
  const int l15  = lane & 15;
  const int lhi  = lane >> 4;

  // XCD-locality remap (T1) + LPT: longest q-tiles first.
  const int flat = blockIdx.x;
  const int slot = flat >> 3;
  const int bh   = (flat & 7) * 4 + (slot & 3);
  const int qt   = 31 - (slot >> 2);
  const int b    = bh >> 4, h = bh & 15;
  const size_t base = (size_t)bh * SEQ * HD;

  u16* Ksh = (u16*)(pool + g * 8192);
  u16* Vsh = (u16*)(pool + 16384 + g * 8192);
  u16* Psh = (u16*)(pool + 32768 + wid * 2304);

  const int qrow = qt * 64 + rw * 16 + l15;
  bf16x8 aq[2];
  aq[0] = *(const bf16x8*)&Q[base + (size_t)qrow * HD + lhi * 8];
  aq[1] = *(const bf16x8*)&Q[base + (size_t)qrow * HD + 32 + lhi * 8];

  f32x4 o[4];
#pragma unroll
  for (int n = 0; n < 4; n++) o[n] = (f32x4){0.f, 0.f, 0.f, 0.f};
  float m_s = -1e30f, l_s = 0.f;

  const int gt   = tid & 255;
  const int srow = gt >> 2;
  const int sd   = (gt & 3) * 16;

  bf16x8 pk0, pk1, pv0, pv1;  // prefetched next-tile K/V (T14)

#define ATTN_LOAD(kt_)                                                            \
  {                                                                               \
    const u16* kp = K + base + (size_t)((kt_) * 64 + srow) * HD + sd;             \
    pk0 = *(const bf16x8*)kp;                                                     \
    pk1 = *(const bf16x8*)(kp + 8);                                               \
    const u16* vp = Vt + base + (size_t)srow * SEQ + (kt_) * 64 + sd;             \
    pv0 = *(const bf16x8*)vp;                                                     \
    pv1 = *(const bf16x8*)(vp + 8);                                               \
  }

  if (g <= qt) ATTN_LOAD(g);

  const int nsteps = qt / 2 + 1;
  for (int it = 0; it < nsteps; ++it) {
    const int kt = 2 * it + g;
    const bool act = (kt <= qt);
    BAR();            // prior tile's LDS reads all consumed -> safe overwrite
    if (act) {        // write prefetched tile into LDS (swizzled both sides)
      *(bf16x8*)&Ksh[srow * 64 + swz(srow, sd)]     = pk0;
      *(bf16x8*)&Ksh[srow * 64 + swz(srow, sd + 8)] = pk1;
      *(bf16x8*)&Vsh[srow * 64 + swz(srow, sd)]     = pv0;
      *(bf16x8*)&Vsh[srow * 64 + swz(srow, sd + 8)] = pv1;
    }
    const int ktn = kt + 2;
    if (ktn <= qt) ATTN_LOAD(ktn);  // stays in flight across compute (no vm drain)
    asm volatile("s_waitcnt lgkmcnt(0)" ::: "memory");  // ds_writes visible
    BAR();
    SCHED0();
    if (act) {
      f32x4 sc[4];
      __builtin_amdgcn_s_setprio(1);
#pragma unroll
      for (int n = 0; n < 4; n++) {
        sc[n] = (f32x4){0.f, 0.f, 0.f, 0.f};
#pragma unroll
        for (int ks = 0; ks < 2; ks++) {
          const int krow = n * 16 + l15;
          bf16x8 bk = *(const bf16x8*)&Ksh[krow * 64 + swz(krow, ks * 32 + lhi * 8)];
          sc[n] = __builtin_amdgcn_mfma_f32_16x16x32_bf16(bk, aq[ks], sc[n], 0, 0, 0);
        }
      }
      __builtin_amdgcn_s_setprio(0);
      if (kt == qt) {  // causal mask on diagonal tile
#pragma unroll
        for (int n = 0; n < 4; n++)
#pragma unroll
          for (int r = 0; r < 4; r++)
            if (kt * 64 + n * 16 + lhi * 4 + r > qrow) sc[n][r] = -1e30f;
      }
      // ---- online softmax, defer-max (T13) ----
      float mx = -1e30f;
#pragma unroll
      for (int n = 0; n < 4; n++)
        mx = fmaxf(mx, fmaxf(fmaxf(sc[n][0], sc[n][1]), fmaxf(sc[n][2], sc[n][3])));
      mx = fmaxf(mx, __shfl_xor(mx, 16, 64));
      mx = fmaxf(mx, __shfl_xor(mx, 32, 64));
      if (__any(mx > m_s + 64.0f)) {  // raw-score THR (e^8 P-bound)
        const float mnew = fmaxf(m_s, mx);
        const float fac = __builtin_amdgcn_exp2f((m_s - mnew) * CEXP);
        l_s *= fac;
        m_s = mnew;
        float facr[4];
#pragma unroll
        for (int r = 0; r < 4; r++) facr[r] = __shfl(fac, lhi * 4 + r, 64);
#pragma unroll
        for (int n = 0; n < 4; n++) {
          o[n][0] *= facr[0]; o[n][1] *= facr[1];
          o[n][2] *= facr[2]; o[n][3] *= facr[3];
        }
      }
      const float nmc = -m_s * CEXP;
      float ps = 0.f;
      u16 pb[4][4];
#pragma unroll
      for (int n = 0; n < 4; n++)
#pragma unroll
        for (int r = 0; r < 4; r++) {
          const float e = __builtin_amdgcn_exp2f(fmaf(sc[n][r], CEXP, nmc));
          ps += e;
          pb[n][r] = f2bf(e);
        }
      ps += __shfl_xor(ps, 16, 64);
      ps += __shfl_xor(ps, 32, 64);
      l_s += ps;
      // P -> per-wave LDS -> A-frag
#pragma unroll
      for (int n = 0; n < 4; n++) {
        ushort4 t; t.x = pb[n][0]; t.y = pb[n][1]; t.z = pb[n][2]; t.w = pb[n][3];
        *(ushort4*)&Psh[l15 * 72 + n * 16 + lhi * 4] = t;
      }
      bf16x8 ap0 = *(const bf16x8*)&Psh[l15 * 72 + lhi * 8];
      bf16x8 ap1 = *(const bf16x8*)&Psh[l15 * 72 + 32 + lhi * 8];
      __builtin_amdgcn_s_setprio(1);
#pragma unroll
      for (int n = 0; n < 4; n++) {
        const int vrow = n * 16 + l15;
        bf16x8 bv0 = *(const bf16x8*)&Vsh[vrow * 64 + swz(vrow, lhi * 8)];
        bf16x8 bv1 = *(const bf16x8*)&Vsh[vrow * 64 + swz(vrow, 32 + lhi * 8)];
        o[n] = __builtin_amdgcn_mfma_f32_16x16x32_bf16(ap0, bv0, o[n], 0, 0, 0);
        o[n] = __builtin_amdgcn_mfma_f32_16x16x32_bf16(ap1, bv1, o[n], 0, 0, 0);
      }
      __builtin_amdgcn_s_setprio(0);
    }
  }
#undef ATTN_LOAD

  __syncthreads();
  float m_o[4], l_o[4];
#pragma unroll
  for (int r = 0; r < 4; r++) {
    m_o[r] = __shfl(m_s, lhi * 4 + r, 64);
    l_o[r] = __shfl(l_s, lhi * 4 + r, 64);
  }

  // merge the two k-groups' partials (pool reused; K/V/P dead)
  f32x4* comb = (f32x4*)pool;
  const int ci = (rw * 64 + lane) * 6;
  if (g == 0) {
#pragma unroll
    for (int n = 0; n < 4; n++) comb[ci + n] = o[n];
    comb[ci + 4] = (f32x4){m_o[0], m_o[1], m_o[2], m_o[3]};
    comb[ci + 5] = (f32x4){l_o[0], l_o[1], l_o[2], l_o[3]};
  }
  __syncthreads();
  if (g == 1) {
    f32x4 m0 = comb[ci + 4];
    f32x4 l0 = comb[ci + 5];
    float a0[4], a1[4], inv[4];
#pragma unroll
    for (int r = 0; r < 4; r++) {
      const float m = fmaxf(m0[r], m_o[r]);
      a0[r] = __builtin_amdgcn_exp2f((m0[r] - m) * CEXP);
      a1[r] = __builtin_amdgcn_exp2f((m_o[r] - m) * CEXP);
      inv[r] = 1.0f / (l0[r] * a0[r] + l_o[r] * a1[r]);
    }
#pragma unroll
    for (int n = 0; n < 4; n++) {
      f32x4 o0 = comb[ci + n];
#pragma unroll
      for (int r = 0; r < 4; r++) {
        const int rowg = qt * 64 + rw * 16 + lhi * 4 + r;
        const float val = (o0[r] * a0[r] + o[n][r] * a1[r]) * inv[r];
        Aout[(((size_t)(b * SEQ + rowg)) << 10) + h * 64 + n * 16 + l15] = f2bf(val);
      }
    }
  }
}

// ---------------- out projection: f32 out = Ab @ Wo^T + bo -------------------
// 128x64 tile, BK=64, async dbuf (48 KB -> 3 blocks/CU), vmcnt(6).
__global__ __launch_bounds__(256) void oproj_kernel(
    const u16* __restrict__ X, const u16* __restrict__ W,
    const float* __restrict__ bias, float* __restrict__ Out) {
  __shared__ u16 As[2][128 * 64];
  __shared__ u16 Bs[2][64 * 64];

  const int tid  = threadIdx.x;
  const int lane = tid & 63;
  const int wid  = tid >> 6;
  const int wm   = wid >> 1, wn = wid & 1;
  const int l15  = lane & 15;
  const int lhi  = lane >> 4;
  const int bm   = blockIdx.x * 128;
  const int bn   = blockIdx.y * 64;

  f32x4 acc[4][2];
#pragma unroll
  for (int i = 0; i < 4; i++)
#pragma unroll
    for (int j = 0; j < 2; j++) acc[i][j] = (f32x4){0.f, 0.f, 0.f, 0.f};

  const int lrow  = lane >> 3;
  const int gcol8 = lane & 7;

#define OPROJ_STAGE(buf, k0)                                                      \
  {                                                                               \
    _Pragma("unroll")                                                             \
    for (int c = 0; c < 4; c++) {                                                 \
      const int row  = c * 32 + wid * 8 + lrow;                                   \
      const int scol = (gcol8 ^ (row & 7)) * 8;                                   \
      gll16(X + (size_t)(bm + row) * HID + (k0) + scol,                           \
            (char*)&As[buf][0] + c * 4096 + wid * 1024);                          \
      if (c < 2)                                                                  \
        gll16(W + (size_t)(bn + row) * HID + (k0) + scol,                         \
              (char*)&Bs[buf][0] + c * 4096 + wid * 1024);                        \
    }                                                                             \
  }

  OPROJ_STAGE(0, 0);
  for (int t = 0; t < 16; t++) {
    BAR();
    if (t < 15) {
      OPROJ_STAGE((t + 1) & 1, (t + 1) * 64);
      asm volatile("s_waitcnt vmcnt(6)" ::: "memory");
    } else {
      asm volatile("s_waitcnt vmcnt(0)" ::: "memory");
    }
    BAR();
    SCHED0();
    const u16* A = &As[t & 1][0];
    const u16* B = &Bs[t & 1][0];
#pragma unroll
    for (int ks = 0; ks < 2; ks++) {
      bf16x8 af[4], bfm[2];
#pragma unroll
      for (int i = 0; i < 4; i++) {
        const int row = wm * 64 + i * 16 + l15;
        af[i] = *(const bf16x8*)&A[row * 64 + swz(row, ks * 32 + lhi * 8)];
      }
#pragma unroll
      for (int j = 0; j < 2; j++) {
        const int row = wn * 32 + j * 16 + l15;
        bfm[j] = *(const bf16x8*)&B[row * 64 + swz(row, ks * 32 + lhi * 8)];
      }
#pragma unroll
      for (int i = 0; i < 4; i++)
#pragma unroll
        for (int j = 0; j < 2; j++)
          acc[i][j] = __builtin_amdgcn_mfma_f32_16x16x32_bf16(af[i], bfm[j], acc[i][j], 0, 0, 0);
    }
  }
#undef OPROJ_STAGE

#pragma unroll
  for (int j = 0; j < 2; j++) {
    const int n = bn + wn * 32 + j * 16 + l15;
    const float bv_ = bias[n];
#pragma unroll
    for (int i = 0; i < 4; i++)
#pragma unroll
      for (int r = 0; r < 4; r++) {
        const int m = bm + wm * 64 + i * 16 + lhi * 4 + r;
        Out[(size_t)m * HID + n] = acc[i][j][r] + bv_;
      }
  }
}

// ---------------- launch ------------------------------------------------------
extern "C" void kernel_launch(void* const* d_in, const int* in_sizes, int n_in,
                              void* d_out, int out_size, void* d_ws, size_t ws_size,
                              hipStream_t stream) {
  const float* q  = (const float*)d_in[0];
  const float* k  = (const float*)d_in[1];
  const float* v  = (const float*)d_in[2];
  const float* Wq = (const float*)d_in[3];
  const float* bq = (const float*)d_in[4];
  const float* Wk = (const float*)d_in[5];
  const float* bk = (const float*)d_in[6];
  const float* Wv = (const float*)d_in[7];
  const float* bv = (const float*)d_in[8];
  const float* Wo = (const float*)d_in[9];
  const float* bo = (const float*)d_in[10];

  u16* ws   = (u16*)d_ws;
  u16* wqkv = ws;                     // Wq,Wk,Wv bf16 @ 0,1M,2M
  u16* wob  = ws + 3u * MEG;          // Wo bf16
  u16* qb   = ws + 4u * MEG;          // q bf16; reused as Ab after proj
  u16* Qb   = ws + 8u * MEG;          // [B,H,S,D]
  u16* Kb   = ws + 12u * MEG;         // [B,H,S,D]
  u16* Vtb  = ws + 16u * MEG;         // [B,H,D,S]
  u16* Ab   = qb;
  u16* kbf  = (u16*)d_out;            // k bf16 in d_out scratch
  u16* vbf  = (u16*)d_out + 4u * MEG; // v bf16

  cvt_kernel<<<dim3(1024, 16), 256, 0, stream>>>(Wq, Wk, Wv, Wo, q, k, v, ws, kbf);

  proj_kernel<<<dim3(32, 16, 3), 256, 0, stream>>>(qb, kbf, vbf, wqkv, bq, bk, bv,
                                                   Qb, Kb, Vtb);

  attn_kernel<<<dim3(1024), 512, 0, stream>>>(Qb, Kb, Vtb, Ab);

  oproj_kernel<<<dim3(32, 16), 256, 0, stream>>>(Ab, wob, bo, (float*)d_out);
}

// Round 15
// 103.603 us; speedup vs baseline: 1.4740x; 1.0107x over previous
//
#include <hip/hip_runtime.h>
#include <hip/hip_bf16.h>

// MHA forward, MI355X gfx950.
// cvt (weights+activations -> bf16) -> batched QKV proj GEMM (128x64 dbuf,
// raw-barrier + counted vmcnt(6)) -> causal flash attn (R13 + l-sum via
// ones-MFMA on the idle matrix pipe) -> out GEMM (async dbuf).
// HIDDEN=1024, HEADS=16, HEAD_DIM=64, B=2, S=2048.

typedef __attribute__((ext_vector_type(4))) float f32x4;
typedef __attribute__((ext_vector_type(8))) short bf16x8;
typedef unsigned short u16;

#define SEQ   2048
#define NH    16
#define HD    64
#define HID   1024
#define CEXP  0.1803368801f  // 0.125 * log2(e)
#define MEG   1048576u

#define BAR()    __builtin_amdgcn_s_barrier()
#define SCHED0() __builtin_amdgcn_sched_barrier(0)

// HW round-to-nearest-even f32->bf16.
static __device__ __forceinline__ u16 f2bf(float f) {
  union { __hip_bfloat16 h; u16 u; } c;
  c.h = __float2bfloat16(f);
  return c.u;
}

// XOR swizzle on 8-elem bf16 chunks within a 64-elem row (T2, G4).
static __device__ __forceinline__ int swz(int row, int col8) {
  return col8 ^ ((row & 7) << 3);
}

// async global->LDS, 16B/lane; lds dest wave-uniform base (guide §5).
static __device__ __forceinline__ void gll16(const void* g, void* l) {
  __builtin_amdgcn_global_load_lds(
      (const __attribute__((address_space(1))) void*)g,
      (__attribute__((address_space(3))) void*)l, 16, 0, 0);
}

// ---------------- f32 -> bf16 conversion: 16 x 1M-elem slices ----------------
__global__ __launch_bounds__(256) void cvt_kernel(
    const float* __restrict__ Wq, const float* __restrict__ Wk,
    const float* __restrict__ Wv, const float* __restrict__ Wo,
    const float* __restrict__ q, const float* __restrict__ k,
    const float* __restrict__ v,
    u16* __restrict__ wsout, u16* __restrict__ dob) {
  const int y = blockIdx.y;
  const int c = y & 3;
  const float* src;
  u16* dst;
  if (y < 4) {
    src = (y == 0) ? Wq : (y == 1) ? Wk : (y == 2) ? Wv : Wo;
    dst = wsout + (size_t)y * MEG;
  } else if (y < 8) {
    src = q + (size_t)c * MEG;
    dst = wsout + 4u * MEG + (size_t)c * MEG;
  } else if (y < 12) {
    src = k + (size_t)c * MEG;
    dst = dob + (size_t)c * MEG;
  } else {
    src = v + (size_t)c * MEG;
    dst = dob + 4u * MEG + (size_t)c * MEG;
  }
  int i = (blockIdx.x * 256 + threadIdx.x) * 4;
  float4 f = *(const float4*)(src + i);
  ushort4 o;
  o.x = f2bf(f.x); o.y = f2bf(f.y); o.z = f2bf(f.z); o.w = f2bf(f.w);
  *(ushort4*)(dst + i) = o;
}

// -------- batched QKV projection: C = X @ W^T + b, scatter to heads ----------
// z=0: Q -> [B,H,S,D]; z=1: K -> [B,H,S,D]; z=2: V -> [B,H,D,S] (transposed).
// 128x64 tile, BK=64, async dbuf: raw s_barrier + counted vmcnt(6).
__global__ __launch_bounds__(256) void proj_kernel(
    const u16* __restrict__ Xq, const u16* __restrict__ Xk,
    const u16* __restrict__ Xv, const u16* __restrict__ Wc,
    const float* __restrict__ bq, const float* __restrict__ bk,
    const float* __restrict__ bvp,
    u16* __restrict__ Qo, u16* __restrict__ Ko, u16* __restrict__ Vto) {
  __shared__ u16 As[2][128 * 64];
  __shared__ u16 Bs[2][64 * 64];

  const int tid  = threadIdx.x;
  const int lane = tid & 63;
  const int wid  = tid >> 6;
  const int wm   = wid >> 1, wn = wid & 1;
  const int l15  = lane & 15;
  const int lhi  = lane >> 4;
  const int z    = blockIdx.z;
  const int bm   = blockIdx.x * 128;
  const int bn   = blockIdx.y * 64;

  const u16* X = (z == 0) ? Xq : (z == 1) ? Xk : Xv;
  const u16* W = Wc + (size_t)z * (HID * HID);
  const float* bias = (z == 0) ? bq : (z == 1) ? bk : bvp;

  f32x4 acc[4][2];
#pragma unroll
  for (int i = 0; i < 4; i++)
#pragma unroll
    for (int j = 0; j < 2; j++) acc[i][j] = (f32x4){0.f, 0.f, 0.f, 0.f};

  const int lrow  = lane >> 3;      // 0..7
  const int gcol8 = lane & 7;       // 8-elem chunk index

#define PROJ_STAGE(buf, k0)                                                       \
  {                                                                               \
    _Pragma("unroll")                                                             \
    for (int c = 0; c < 4; c++) {                                                 \
      const int row  = c * 32 + wid * 8 + lrow;                                   \
      const int scol = (gcol8 ^ (row & 7)) * 8; /* inverse-swizzled source */     \
      gll16(X + (size_t)(bm + row) * HID + (k0) + scol,                           \
            (char*)&As[buf][0] + c * 4096 + wid * 1024);                          \
      if (c < 2)                                                                  \
        gll16(W + (size_t)(bn + row) * HID + (k0) + scol,                         \
              (char*)&Bs[buf][0] + c * 4096 + wid * 1024);                        \
    }                                                                             \
  }

  PROJ_STAGE(0, 0);
  for (int t = 0; t < 16; t++) {
    BAR();  // prev compute done on all waves -> safe to overwrite buf[(t+1)&1]
    if (t < 15) {
      PROJ_STAGE((t + 1) & 1, (t + 1) * 64);
      asm volatile("s_waitcnt vmcnt(6)" ::: "memory");  // tile t landed; t+1 in flight
    } else {
      asm volatile("s_waitcnt vmcnt(0)" ::: "memory");
    }
    BAR();  // all waves' tile-t loads visible
    SCHED0();
    const u16* A = &As[t & 1][0];
    const u16* B = &Bs[t & 1][0];
#pragma unroll
    for (int ks = 0; ks < 2; ks++) {
      bf16x8 af[4], bfm[2];
#pragma unroll
      for (int i = 0; i < 4; i++) {
        const int row = wm * 64 + i * 16 + l15;
        af[i] = *(const bf16x8*)&A[row * 64 + swz(row, ks * 32 + lhi * 8)];
      }
#pragma unroll
      for (int j = 0; j < 2; j++) {
        const int row = wn * 32 + j * 16 + l15;
        bfm[j] = *(const bf16x8*)&B[row * 64 + swz(row, ks * 32 + lhi * 8)];
      }
#pragma unroll
      for (int i = 0; i < 4; i++)
#pragma unroll
        for (int j = 0; j < 2; j++)
          acc[i][j] = __builtin_amdgcn_mfma_f32_16x16x32_bf16(af[i], bfm[j], acc[i][j], 0, 0, 0);
    }
  }
#undef PROJ_STAGE

  // epilogue: bias + scatter to heads
  const int bb = bm >> 11;  // tile never crosses batch
#pragma unroll
  for (int j = 0; j < 2; j++) {
    const int n = bn + wn * 32 + j * 16 + l15;
    const float bv_ = bias[n];
    const int h = n >> 6, d = n & 63;
    if (z == 2) {
#pragma unroll
      for (int i = 0; i < 4; i++) {
        const int s0 = (bm + wm * 64 + i * 16 + lhi * 4) & 2047;
        ushort4 t;
        t.x = f2bf(acc[i][j][0] + bv_);
        t.y = f2bf(acc[i][j][1] + bv_);
        t.z = f2bf(acc[i][j][2] + bv_);
        t.w = f2bf(acc[i][j][3] + bv_);
        *(ushort4*)&Vto[((size_t)(bb * NH + h) * HD + d) * SEQ + s0] = t;
      }
    } else {
      u16* O = z ? Ko : Qo;
#pragma unroll
      for (int i = 0; i < 4; i++)
#pragma unroll
        for (int r = 0; r < 4; r++) {
          const int m = bm + wm * 64 + i * 16 + lhi * 4 + r;
          const int s = m & 2047;
          O[(((size_t)(bb * NH + h) * SEQ + s) << 6) + d] = f2bf(acc[i][j][r] + bv_);
        }
    }
  }
}

// ---------------- causal flash attention -------------------------------------
// Q,K: bf16 [B,H,S,D]; Vt: bf16 [B,H,D,S]; out: bf16 [B,S,H*D].
// 512 thr = 2 k-groups x 4 row-waves; swapped QK^T (lane = one q-row).
// l-sum computed on the MFMA pipe: lacc = mfma(P, ones) accumulates sum_k P
// per q-row directly in o-layout (removes 16 VALU adds + 2 bpermutes/step).
__global__ __launch_bounds__(512) void attn_kernel(
    const u16* __restrict__ Q, const u16* __restrict__ K,
    const u16* __restrict__ Vt, u16* __restrict__ Aout) {
  __shared__ __align__(16) char pool[51200];

  const int tid  = threadIdx.x;
  const int lane = tid & 63;
  const int wid  = tid >> 6;
  const int rw   = wid & 3;
  const int g    = wid >> 2;
  const int l15  = lane & 15;
  const int lhi  = lane >> 4;

  // XCD-locality remap (T1) + LPT: longest q-tiles first.
  const int flat = blockIdx.x;
  const int slot = flat >> 3;
  const int bh   = (flat & 7) * 4 + (slot & 3);
  const int qt   = 31 - (slot >> 2);
  const int b    = bh >> 4, h = bh & 15;
  const size_t base = (size_t)bh * SEQ * HD;

  u16* Ksh = (u16*)(pool + g * 8192);
  u16* Vsh = (u16*)(pool + 16384 + g * 8192);
  u16* Psh = (u16*)(pool + 32768 + wid * 2304);

  const int qrow = qt * 64 + rw * 16 + l15;
  bf16x8 aq[2];
  aq[0] = *(const bf16x8*)&Q[base + (size_t)qrow * HD + lhi * 8];
  aq[1] = *(const bf16x8*)&Q[base + (size_t)qrow * HD + 32 + lhi * 8];

  bf16x8 ones;
#pragma unroll
  for (int j = 0; j < 8; j++) ones[j] = (short)0x3F80;  // bf16 1.0

  f32x4 o[4];
#pragma unroll
  for (int n = 0; n < 4; n++) o[n] = (f32x4){0.f, 0.f, 0.f, 0.f};
  f32x4 lacc = (f32x4){0.f, 0.f, 0.f, 0.f};  // sum_k P, o-layout rows
  float m_s = -1e30f;

  const int gt   = tid & 255;
  const int srow = gt >> 2;
  const int sd   = (gt & 3) * 16;

  bf16x8 pk0, pk1, pv0, pv1;  // prefetched next-tile K/V (T14)

#define ATTN_LOAD(kt_)                                                            \
  {                                                                               \
    const u16* kp = K + base + (size_t)((kt_) * 64 + srow) * HD + sd;             \
    pk0 = *(const bf16x8*)kp;                                                     \
    pk1 = *(const bf16x8*)(kp + 8);                                               \
    const u16* vp = Vt + base + (size_t)srow * SEQ + (kt_) * 64 + sd;             \
    pv0 = *(const bf16x8*)vp;                                                     \
    pv1 = *(const bf16x8*)(vp + 8);                                               \
  }

  if (g <= qt) ATTN_LOAD(g);

  const int nsteps = qt / 2 + 1;
  for (int it = 0; it < nsteps; ++it) {
    const int kt = 2 * it + g;
    const bool act = (kt <= qt);
    BAR();            // prior tile's LDS reads all consumed -> safe overwrite
    if (act) {        // write prefetched tile into LDS (swizzled both sides)
      *(bf16x8*)&Ksh[srow * 64 + swz(srow, sd)]     = pk0;
      *(bf16x8*)&Ksh[srow * 64 + swz(srow, sd + 8)] = pk1;
      *(bf16x8*)&Vsh[srow * 64 + swz(srow, sd)]     = pv0;
      *(bf16x8*)&Vsh[srow * 64 + swz(srow, sd + 8)] = pv1;
    }
    const int ktn = kt + 2;
    if (ktn <= qt) ATTN_LOAD(ktn);  // stays in flight across compute (no vm drain)
    asm volatile("s_waitcnt lgkmcnt(0)" ::: "memory");  // ds_writes visible
    BAR();
    SCHED0();
    if (act) {
      f32x4 sc[4];
      __builtin_amdgcn_s_setprio(1);
#pragma unroll
      for (int n = 0; n < 4; n++) {
        sc[n] = (f32x4){0.f, 0.f, 0.f, 0.f};
#pragma unroll
        for (int ks = 0; ks < 2; ks++) {
          const int krow = n * 16 + l15;
          bf16x8 bk = *(const bf16x8*)&Ksh[krow * 64 + swz(krow, ks * 32 + lhi * 8)];
          sc[n] = __builtin_amdgcn_mfma_f32_16x16x32_bf16(bk, aq[ks], sc[n], 0, 0, 0);
        }
      }
      __builtin_amdgcn_s_setprio(0);
      if (kt == qt) {  // causal mask on diagonal tile
#pragma unroll
        for (int n = 0; n < 4; n++)
#pragma unroll
          for (int r = 0; r < 4; r++)
            if (kt * 64 + n * 16 + lhi * 4 + r > qrow) sc[n][r] = -1e30f;
      }
      // ---- online softmax, defer-max (T13); l handled by MFMA below ----
      float mx = -1e30f;
#pragma unroll
      for (int n = 0; n < 4; n++)
        mx = fmaxf(mx, fmaxf(fmaxf(sc[n][0], sc[n][1]), fmaxf(sc[n][2], sc[n][3])));
      mx = fmaxf(mx, __shfl_xor(mx, 16, 64));
      mx = fmaxf(mx, __shfl_xor(mx, 32, 64));
      if (__any(mx > m_s + 64.0f)) {  // raw-score THR (e^8 P-bound)
        const float mnew = fmaxf(m_s, mx);
        const float fac = __builtin_amdgcn_exp2f((m_s - mnew) * CEXP);
        m_s = mnew;
        float facr[4];
#pragma unroll
        for (int r = 0; r < 4; r++) facr[r] = __shfl(fac, lhi * 4 + r, 64);
#pragma unroll
        for (int n = 0; n < 4; n++) {
          o[n][0] *= facr[0]; o[n][1] *= facr[1];
          o[n][2] *= facr[2]; o[n][3] *= facr[3];
        }
        lacc[0] *= facr[0]; lacc[1] *= facr[1];
        lacc[2] *= facr[2]; lacc[3] *= facr[3];
      }
      const float nmc = -m_s * CEXP;
      u16 pb[4][4];
#pragma unroll
      for (int n = 0; n < 4; n++)
#pragma unroll
        for (int r = 0; r < 4; r++)
          pb[n][r] = f2bf(__builtin_amdgcn_exp2f(fmaf(sc[n][r], CEXP, nmc)));
      // P -> per-wave LDS -> A-frag
#pragma unroll
      for (int n = 0; n < 4; n++) {
        ushort4 t; t.x = pb[n][0]; t.y = pb[n][1]; t.z = pb[n][2]; t.w = pb[n][3];
        *(ushort4*)&Psh[l15 * 72 + n * 16 + lhi * 4] = t;
      }
      bf16x8 ap0 = *(const bf16x8*)&Psh[l15 * 72 + lhi * 8];
      bf16x8 ap1 = *(const bf16x8*)&Psh[l15 * 72 + 32 + lhi * 8];
      __builtin_amdgcn_s_setprio(1);
      // l-sum on the matrix pipe: lacc[r] += sum_k P[q=lhi*4+r][k]
      lacc = __builtin_amdgcn_mfma_f32_16x16x32_bf16(ap0, ones, lacc, 0, 0, 0);
      lacc = __builtin_amdgcn_mfma_f32_16x16x32_bf16(ap1, ones, lacc, 0, 0, 0);
#pragma unroll
      for (int n = 0; n < 4; n++) {
        const int vrow = n * 16 + l15;
        bf16x8 bv0 = *(const bf16x8*)&Vsh[vrow * 64 + swz(vrow, lhi * 8)];
        bf16x8 bv1 = *(const bf16x8*)&Vsh[vrow * 64 + swz(vrow, 32 + lhi * 8)];
        o[n] = __builtin_amdgcn_mfma_f32_16x16x32_bf16(ap0, bv0, o[n], 0, 0, 0);
        o[n] = __builtin_amdgcn_mfma_f32_16x16x32_bf16(ap1, bv1, o[n], 0, 0, 0);
      }
      __builtin_amdgcn_s_setprio(0);
    }
  }
#undef ATTN_LOAD

  __syncthreads();
  // m still per-q-lane (l15 = q); redistribute into o-layout rows for merge
  float m_o[4];
#pragma unroll
  for (int r = 0; r < 4; r++) m_o[r] = __shfl(m_s, lhi * 4 + r, 64);

  // merge the two k-groups' partials (pool reused; K/V/P dead)
  f32x4* comb = (f32x4*)pool;
  const int ci = (rw * 64 + lane) * 6;
  if (g == 0) {
#pragma unroll
    for (int n = 0; n < 4; n++) comb[ci + n] = o[n];
    comb[ci + 4] = (f32x4){m_o[0], m_o[1], m_o[2], m_o[3]};
    comb[ci + 5] = lacc;
  }
  __syncthreads();
  if (g == 1) {
    f32x4 m0 = comb[ci + 4];
    f32x4 l0 = comb[ci + 5];
    float a0[4], a1[4], inv[4];
#pragma unroll
    for (int r = 0; r < 4; r++) {
      const float m = fmaxf(m0[r], m_o[r]);
      a0[r] = __builtin_amdgcn_exp2f((m0[r] - m) * CEXP);
      a1[r] = __builtin_amdgcn_exp2f((m_o[r] - m) * CEXP);
      inv[r] = 1.0f / (l0[r] * a0[r] + lacc[r] * a1[r]);
    }
#pragma unroll
    for (int n = 0; n < 4; n++) {
      f32x4 o0 = comb[ci + n];
#pragma unroll
      for (int r = 0; r < 4; r++) {
        const int rowg = qt * 64 + rw * 16 + lhi * 4 + r;
        const float val = (o0[r] * a0[r] + o[n][r] * a1[r]) * inv[r];
        Aout[(((size_t)(b * SEQ + rowg)) << 10) + h * 64 + n * 16 + l15] = f2bf(val);
      }
    }
  }
}

// ---------------- out projection: f32 out = Ab @ Wo^T + bo -------------------
// 128x64 tile, BK=64, async dbuf (48 KB -> 3 blocks/CU), vmcnt(6).
__global__ __launch_bounds__(256) void oproj_kernel(
    const u16* __restrict__ X, const u16* __restrict__ W,
    const float* __restrict__ bias, float* __restrict__ Out) {
  __shared__ u16 As[2][128 * 64];
  __shared__ u16 Bs[2][64 * 64];

  const int tid  = threadIdx.x;
  const int lane = tid & 63;
  const int wid  = tid >> 6;
  const int wm   = wid >> 1, wn = wid & 1;
  const int l15  = lane & 15;
  const int lhi  = lane >> 4;
  const int bm   = blockIdx.x * 128;
  const int bn   = blockIdx.y * 64;

  f32x4 acc[4][2];
#pragma unroll
  for (int i = 0; i < 4; i++)
#pragma unroll
    for (int j = 0; j < 2; j++) acc[i][j] = (f32x4){0.f, 0.f, 0.f, 0.f};

  const int lrow  = lane >> 3;
  const int gcol8 = lane & 7;

#define OPROJ_STAGE(buf, k0)                                                      \
  {                                                                               \
    _Pragma("unroll")                                                             \
    for (int c = 0; c < 4; c++) {                                                 \
      const int row  = c * 32 + wid * 8 + lrow;                                   \
      const int scol = (gcol8 ^ (row & 7)) * 8;                                   \
      gll16(X + (size_t)(bm + row) * HID + (k0) + scol,                           \
            (char*)&As[buf][0] + c * 4096 + wid * 1024);                          \
      if (c < 2)                                                                  \
        gll16(W + (size_t)(bn + row) * HID + (k0) + scol,                         \
              (char*)&Bs[buf][0] + c * 4096 + wid * 1024);                        \
    }                                                                             \
  }

  OPROJ_STAGE(0, 0);
  for (int t = 0; t < 16; t++) {
    BAR();
    if (t < 15) {
      OPROJ_STAGE((t + 1) & 1, (t + 1) * 64);
      asm volatile("s_waitcnt vmcnt(6)" ::: "memory");
    } else {
      asm volatile("s_waitcnt vmcnt(0)" ::: "memory");
    }
    BAR();
    SCHED0();
    const u16* A = &As[t & 1][0];
    const u16* B = &Bs[t & 1][0];
#pragma unroll
    for (int ks = 0; ks < 2; ks++) {
      bf16x8 af[4], bfm[2];
#pragma unroll
      for (int i = 0; i < 4; i++) {
        const int row = wm * 64 + i * 16 + l15;
        af[i] = *(const bf16x8*)&A[row * 64 + swz(row, ks * 32 + lhi * 8)];
      }
#pragma unroll
      for (int j = 0; j < 2; j++) {
        const int row = wn * 32 + j * 16 + l15;
        bfm[j] = *(const bf16x8*)&B[row * 64 + swz(row, ks * 32 + lhi * 8)];
      }
#pragma unroll
      for (int i = 0; i < 4; i++)
#pragma unroll
        for (int j = 0; j < 2; j++)
          acc[i][j] = __builtin_amdgcn_mfma_f32_16x16x32_bf16(af[i], bfm[j], acc[i][j], 0, 0, 0);
    }
  }
#undef OPROJ_STAGE

#pragma unroll
  for (int j = 0; j < 2; j++) {
    const int n = bn + wn * 32 + j * 16 + l15;
    const float bv_ = bias[n];
#pragma unroll
    for (int i = 0; i < 4; i++)
#pragma unroll
      for (int r = 0; r < 4; r++) {
        const int m = bm + wm * 64 + i * 16 + lhi * 4 + r;
        Out[(size_t)m * HID + n] = acc[i][j][r] + bv_;
      }
  }
}

// ---------------- launch ------------------------------------------------------
extern "C" void kernel_launch(void* const* d_in, const int* in_sizes, int n_in,
                              void* d_out, int out_size, void* d_ws, size_t ws_size,
                              hipStream_t stream) {
  const float* q  = (const float*)d_in[0];
  const float* k  = (const float*)d_in[1];
  const float* v  = (const float*)d_in[2];
  const float* Wq = (const float*)d_in[3];
  const float* bq = (const float*)d_in[4];
  const float* Wk = (const float*)d_in[5];
  const float* bk = (const float*)d_in[6];
  const float* Wv = (const float*)d_in[7];
  const float* bv = (const float*)d_in[8];
  const float* Wo = (const float*)d_in[9];
  const float* bo = (const float*)d_in[10];

  u16* ws   = (u16*)d_ws;
  u16* wqkv = ws;                     // Wq,Wk,Wv bf16 @ 0,1M,2M
  u16* wob  = ws + 3u * MEG;          // Wo bf16
  u16* qb   = ws + 4u * MEG;          // q bf16; reused as Ab after proj
  u16* Qb   = ws + 8u * MEG;          // [B,H,S,D]
  u16* Kb   = ws + 12u * MEG;         // [B,H,S,D]
  u16* Vtb  = ws + 16u * MEG;         // [B,H,D,S]
  u16* Ab   = qb;
  u16* kbf  = (u16*)d_out;            // k bf16 in d_out scratch
  u16* vbf  = (u16*)d_out + 4u * MEG; // v bf16

  cvt_kernel<<<dim3(1024, 16), 256, 0, stream>>>(Wq, Wk, Wv, Wo, q, k, v, ws, kbf);

  proj_kernel<<<dim3(32, 16, 3), 256, 0, stream>>>(qb, kbf, vbf, wqkv, bq, bk, bv,
                                                   Qb, Kb, Vtb);

  attn_kernel<<<dim3(1024), 512, 0, stream>>>(Qb, Kb, Vtb, Ab);

  oproj_kernel<<<dim3(32, 16), 256, 0, stream>>>(Ab, wob, bo, (float*)d_out);
}

// Round 17
// 99.133 us; speedup vs baseline: 1.5405x; 1.0451x over previous
//
#include <hip/hip_runtime.h>
#include <hip/hip_bf16.h>

// MHA forward, MI355X gfx950.
// cvt (weights+activations -> bf16) -> batched QKV proj GEMM (128x64 dbuf,
// raw-barrier + counted vmcnt(6)) -> causal flash attn (32x32x16 MFMA,
// QBLK=128, 4 q-waves x 2 k-groups, in-register P, s-permuted V LDS,
// in-lane softmax, act-guarded causal frontier) -> out GEMM (async dbuf).
// HIDDEN=1024, HEADS=16, HEAD_DIM=64, B=2, S=2048.

typedef __attribute__((ext_vector_type(4)))  float f32x4;
typedef __attribute__((ext_vector_type(16))) float f32x16;
typedef __attribute__((ext_vector_type(8)))  short bf16x8;
typedef unsigned short u16;

#define SEQ   2048
#define NH    16
#define HD    64
#define HID   1024
#define CEXP  0.1803368801f  // 0.125 * log2(e)
#define MEG   1048576u
#define MASKV (-30000.0f)    // masked raw score: exp2((-3e4-m)*CEXP) == 0, no inf

#define BAR()    __builtin_amdgcn_s_barrier()
#define SCHED0() __builtin_amdgcn_sched_barrier(0)

// HW round-to-nearest-even f32->bf16.
static __device__ __forceinline__ u16 f2bf(float f) {
  union { __hip_bfloat16 h; u16 u; } c;
  c.h = __float2bfloat16(f);
  return c.u;
}

// XOR swizzle on 8-elem bf16 chunks within a 64-elem row (T2, G4).
static __device__ __forceinline__ int swz(int row, int col8) {
  return col8 ^ ((row & 7) << 3);
}

// async global->LDS, 16B/lane; lds dest wave-uniform base (guide §5).
static __device__ __forceinline__ void gll16(const void* g, void* l) {
  __builtin_amdgcn_global_load_lds(
      (const __attribute__((address_space(1))) void*)g,
      (__attribute__((address_space(3))) void*)l, 16, 0, 0);
}

// ---------------- f32 -> bf16 conversion: 16 x 1M-elem slices ----------------
__global__ __launch_bounds__(256) void cvt_kernel(
    const float* __restrict__ Wq, const float* __restrict__ Wk,
    const float* __restrict__ Wv, const float* __restrict__ Wo,
    const float* __restrict__ q, const float* __restrict__ k,
    const float* __restrict__ v,
    u16* __restrict__ wsout, u16* __restrict__ dob) {
  const int y = blockIdx.y;
  const int c = y & 3;
  const float* src;
  u16* dst;
  if (y < 4) {
    src = (y == 0) ? Wq : (y == 1) ? Wk : (y == 2) ? Wv : Wo;
    dst = wsout + (size_t)y * MEG;
  } else if (y < 8) {
    src = q + (size_t)c * MEG;
    dst = wsout + 4u * MEG + (size_t)c * MEG;
  } else if (y < 12) {
    src = k + (size_t)c * MEG;
    dst = dob + (size_t)c * MEG;
  } else {
    src = v + (size_t)c * MEG;
    dst = dob + 4u * MEG + (size_t)c * MEG;
  }
  int i = (blockIdx.x * 256 + threadIdx.x) * 4;
  float4 f = *(const float4*)(src + i);
  ushort4 o;
  o.x = f2bf(f.x); o.y = f2bf(f.y); o.z = f2bf(f.z); o.w = f2bf(f.w);
  *(ushort4*)(dst + i) = o;
}

// -------- batched QKV projection: C = X @ W^T + b, scatter to heads ----------
// z=0: Q -> [B,H,S,D]; z=1: K -> [B,H,S,D]; z=2: V -> [B,H,D,S] (transposed).
// 128x64 tile, BK=64, async dbuf: raw s_barrier + counted vmcnt(6).
__global__ __launch_bounds__(256) void proj_kernel(
    const u16* __restrict__ Xq, const u16* __restrict__ Xk,
    const u16* __restrict__ Xv, const u16* __restrict__ Wc,
    const float* __restrict__ bq, const float* __restrict__ bk,
    const float* __restrict__ bvp,
    u16* __restrict__ Qo, u16* __restrict__ Ko, u16* __restrict__ Vto) {
  __shared__ u16 As[2][128 * 64];
  __shared__ u16 Bs[2][64 * 64];

  const int tid  = threadIdx.x;
  const int lane = tid & 63;
  const int wid  = tid >> 6;
  const int wm   = wid >> 1, wn = wid & 1;
  const int l15  = lane & 15;
  const int lhi  = lane >> 4;
  const int z    = blockIdx.z;
  const int bm   = blockIdx.x * 128;
  const int bn   = blockIdx.y * 64;

  const u16* X = (z == 0) ? Xq : (z == 1) ? Xk : Xv;
  const u16* W = Wc + (size_t)z * (HID * HID);
  const float* bias = (z == 0) ? bq : (z == 1) ? bk : bvp;

  f32x4 acc[4][2];
#pragma unroll
  for (int i = 0; i < 4; i++)
#pragma unroll
    for (int j = 0; j < 2; j++) acc[i][j] = (f32x4){0.f, 0.f, 0.f, 0.f};

  const int lrow  = lane >> 3;      // 0..7
  const int gcol8 = lane & 7;       // 8-elem chunk index

#define PROJ_STAGE(buf, k0)                                                       \
  {                                                                               \
    _Pragma("unroll")                                                             \
    for (int c = 0; c < 4; c++) {                                                 \
      const int row  = c * 32 + wid * 8 + lrow;                                   \
      const int scol = (gcol8 ^ (row & 7)) * 8; /* inverse-swizzled source */     \
      gll16(X + (size_t)(bm + row) * HID + (k0) + scol,                           \
            (char*)&As[buf][0] + c * 4096 + wid * 1024);                          \
      if (c < 2)                                                                  \
        gll16(W + (size_t)(bn + row) * HID + (k0) + scol,                         \
              (char*)&Bs[buf][0] + c * 4096 + wid * 1024);                        \
    }                                                                             \
  }

  PROJ_STAGE(0, 0);
  for (int t = 0; t < 16; t++) {
    BAR();  // prev compute done on all waves -> safe to overwrite buf[(t+1)&1]
    if (t < 15) {
      PROJ_STAGE((t + 1) & 1, (t + 1) * 64);
      asm volatile("s_waitcnt vmcnt(6)" ::: "memory");  // tile t landed; t+1 in flight
    } else {
      asm volatile("s_waitcnt vmcnt(0)" ::: "memory");
    }
    BAR();  // all waves' tile-t loads visible
    SCHED0();
    const u16* A = &As[t & 1][0];
    const u16* B = &Bs[t & 1][0];
#pragma unroll
    for (int ks = 0; ks < 2; ks++) {
      bf16x8 af[4], bfm[2];
#pragma unroll
      for (int i = 0; i < 4; i++) {
        const int row = wm * 64 + i * 16 + l15;
        af[i] = *(const bf16x8*)&A[row * 64 + swz(row, ks * 32 + lhi * 8)];
      }
#pragma unroll
      for (int j = 0; j < 2; j++) {
        const int row = wn * 32 + j * 16 + l15;
        bfm[j] = *(const bf16x8*)&B[row * 64 + swz(row, ks * 32 + lhi * 8)];
      }
#pragma unroll
      for (int i = 0; i < 4; i++)
#pragma unroll
        for (int j = 0; j < 2; j++)
          acc[i][j] = __builtin_amdgcn_mfma_f32_16x16x32_bf16(af[i], bfm[j], acc[i][j], 0, 0, 0);
    }
  }
#undef PROJ_STAGE

  // epilogue: bias + scatter to heads
  const int bb = bm >> 11;  // tile never crosses batch
#pragma unroll
  for (int j = 0; j < 2; j++) {
    const int n = bn + wn * 32 + j * 16 + l15;
    const float bv_ = bias[n];
    const int h = n >> 6, d = n & 63;
    if (z == 2) {
#pragma unroll
      for (int i = 0; i < 4; i++) {
        const int s0 = (bm + wm * 64 + i * 16 + lhi * 4) & 2047;
        ushort4 t;
        t.x = f2bf(acc[i][j][0] + bv_);
        t.y = f2bf(acc[i][j][1] + bv_);
        t.z = f2bf(acc[i][j][2] + bv_);
        t.w = f2bf(acc[i][j][3] + bv_);
        *(ushort4*)&Vto[((size_t)(bb * NH + h) * HD + d) * SEQ + s0] = t;
      }
    } else {
      u16* O = z ? Ko : Qo;
#pragma unroll
      for (int i = 0; i < 4; i++)
#pragma unroll
        for (int r = 0; r < 4; r++) {
          const int m = bm + wm * 64 + i * 16 + lhi * 4 + r;
          const int s = m & 2047;
          O[(((size_t)(bb * NH + h) * SEQ + s) << 6) + d] = f2bf(acc[i][j][r] + bv_);
        }
    }
  }
}

// ---------------- causal flash attention (32x32x16, v2 fixed) ----------------
// Q,K: bf16 [B,H,S,D]; Vt: bf16 [B,H,D,S]; out: bf16 [B,S,H*D].
// 512 thr = 4 q-waves (32 rows each) x 2 k-groups. QBLK=128, KT=64.
// Swapped QK^T (q = col = lane&31): softmax fully in-lane + 1 xor-32 shuffle.
// P stays in registers; V LDS s-permuted so PV B-frag = one ds_read_b128.
// act guard: skip wave-tiles entirely above the causal frontier (NaN fix).
__global__ __launch_bounds__(512) void attn_kernel(
    const u16* __restrict__ Q, const u16* __restrict__ K,
    const u16* __restrict__ Vt, u16* __restrict__ Aout) {
  // group g: K @ g*16384 ([64][64] swz), V @ g*16384+8192 (perm+swz)
  // merge scratch reuses pool: 4 waves x 64 lanes x 144 B = 36864 B.
  __shared__ __align__(16) char pool[36864];

  const int tid  = threadIdx.x;
  const int lane = tid & 63;
  const int wid  = tid >> 6;       // 0..7
  const int wq   = wid & 3;        // q-block 0..3 (rows wq*32..+32)
  const int g    = wid >> 2;       // k-group (kt parity)
  const int l31  = lane & 31;
  const int gp   = lane >> 5;      // operand k-slot half

  // XCD remap (T1) + LPT. 512 blocks (16 qt x 32 bh), all co-resident.
  const int flat = blockIdx.x;
  const int slot = flat >> 3;                  // 0..63
  const int bh   = (flat & 7) * 4 + (slot & 3);
  const int qt   = 15 - (slot >> 2);           // 128-row q tile
  const int b    = bh >> 4, h = bh & 15;
  const size_t base = (size_t)bh * SEQ * HD;

  const int qrow = qt * 128 + wq * 32 + l31;   // this lane's q-row (q = col)
  const int qmax = qt * 128 + wq * 32 + 31;    // wave's causal frontier
  bf16x8 aq[4];                                 // Q[qrow][16ds+8gp .. +8]
#pragma unroll
  for (int ds = 0; ds < 4; ds++)
    aq[ds] = *(const bf16x8*)&Q[base + (size_t)qrow * HD + ds * 16 + gp * 8];

  f32x16 o[2];
#pragma unroll
  for (int r = 0; r < 16; r++) { o[0][r] = 0.f; o[1][r] = 0.f; }
  float m_s = -1e30f, l_s = 0.f;

  // staging: threads 0..255 stage group-0 tile, 256..511 group-1 tile.
  const int st   = tid & 255;
  const int gs   = tid >> 8;
  const int srow = st >> 2;         // 0..63
  const int sd   = (st & 3) * 16;
  const int kc0  = sd >> 3;         // chunk base (0,2,4,6)
  u16* Ks_s = (u16*)(pool + gs * 16384);
  u16* Vs_s = (u16*)(pool + gs * 16384 + 8192);
  const int kwz0 = srow * 64 + ((kc0       ^ (srow & 7)) << 3);
  const int kwz1 = srow * 64 + (((kc0 + 1) ^ (srow & 7)) << 3);

  union B2S { bf16x8 v; short4 s[2]; };
  B2S pk0, pk1, pv0, pv1;  // prefetched tile (T14)

#define LOADR(kt_)                                                                \
  {                                                                               \
    const u16* kp = K + base + (size_t)((kt_) * 64 + srow) * HD + sd;             \
    pk0.v = *(const bf16x8*)kp;                                                   \
    pk1.v = *(const bf16x8*)(kp + 8);                                             \
    const u16* vp = Vt + base + (size_t)srow * SEQ + (kt_) * 64 + sd;             \
    pv0.v = *(const bf16x8*)vp;                                                   \
    pv1.v = *(const bf16x8*)(vp + 8);                                             \
  }

  LOADR(gs);

  const int nit = qt + 1;
  for (int it = 0; it < nit; ++it) {
    BAR();   // prior tile's LDS reads consumed -> safe overwrite
    // K: linear chunks; V: s-perm [sd+0..3, sd+8..11 | sd+4..7, sd+12..15]
    *(bf16x8*)&Ks_s[kwz0] = pk0.v;
    *(bf16x8*)&Ks_s[kwz1] = pk1.v;
    *(short4*)&Vs_s[kwz0]     = pv0.s[0];
    *(short4*)&Vs_s[kwz0 + 4] = pv1.s[0];
    *(short4*)&Vs_s[kwz1]     = pv0.s[1];
    *(short4*)&Vs_s[kwz1 + 4] = pv1.s[1];
    if (it + 1 < nit) LOADR(2 * (it + 1) + gs);  // in flight across compute
    asm volatile("s_waitcnt lgkmcnt(0)" ::: "memory");
    BAR();
    SCHED0();

    const int kt = 2 * it + g;
    const bool act = (kt * 64) <= qmax;  // wave-uniform: tile has valid work
    if (act) {
      const u16* Ksh = (const u16*)(pool + g * 16384);
      const u16* Vsh = (const u16*)(pool + g * 16384 + 8192);

      // ---- S^T = mfma(K, Q): sc[kb] rows = kseq, col = q = l31 ----
      f32x16 sc[2];
      __builtin_amdgcn_s_setprio(1);
#pragma unroll
      for (int kb = 0; kb < 2; kb++) {
#pragma unroll
        for (int r = 0; r < 16; r++) sc[kb][r] = 0.f;
#pragma unroll
        for (int ds = 0; ds < 4; ds++) {
          const int row = kb * 32 + l31;
          bf16x8 kf = *(const bf16x8*)&Ksh[row * 64 + (((2 * ds + gp) ^ (row & 7)) << 3)];
          sc[kb] = __builtin_amdgcn_mfma_f32_32x32x16_bf16(kf, aq[ds], sc[kb], 0, 0, 0);
        }
      }
      __builtin_amdgcn_s_setprio(0);

      if (kt >= 2 * qt) {  // causal mask (diagonal-adjacent tiles)
#pragma unroll
        for (int kb = 0; kb < 2; kb++)
#pragma unroll
          for (int r = 0; r < 16; r++) {
            const int kg = kt * 64 + kb * 32 + (r & 3) + 8 * (r >> 2) + 4 * gp;
            if (kg > qrow) sc[kb][r] = MASKV;
          }
      }

      // ---- online softmax (in-lane + 1 shuffle), defer-max (T13) ----
      float mx = -1e30f;
#pragma unroll
      for (int kb = 0; kb < 2; kb++)
#pragma unroll
        for (int r = 0; r < 16; r++) mx = fmaxf(mx, sc[kb][r]);
      mx = fmaxf(mx, __shfl_xor(mx, 32, 64));
      if (__any(mx > m_s + 64.0f)) {  // raw-score THR (e^8 P-bound)
        const float mnew = fmaxf(m_s, mx);
        const float fac = __builtin_amdgcn_exp2f((m_s - mnew) * CEXP);
        l_s *= fac;
        m_s = mnew;
        float facr[16];
#pragma unroll
        for (int r = 0; r < 16; r++)
          facr[r] = __shfl(fac, (r & 3) + 8 * (r >> 2) + 4 * gp, 64);
#pragma unroll
        for (int r = 0; r < 16; r++) { o[0][r] *= facr[r]; o[1][r] *= facr[r]; }
      }
      const float nmc = -m_s * CEXP;
      float ps = 0.f;
#pragma unroll
      for (int kb = 0; kb < 2; kb++)
#pragma unroll
        for (int r = 0; r < 16; r++) {
          const float e = __builtin_amdgcn_exp2f(fmaf(sc[kb][r], CEXP, nmc));
          sc[kb][r] = e;
          ps += e;
        }
      ps += __shfl_xor(ps, 32, 64);
      l_s += ps;

      // ---- O += P V : A-slice (kb,ss) = bf16(sc[kb] regs ss*8..+8) ----
      __builtin_amdgcn_s_setprio(1);
#pragma unroll
      for (int kb = 0; kb < 2; kb++)
#pragma unroll
        for (int ss = 0; ss < 2; ss++) {
          bf16x8 pa;
#pragma unroll
          for (int j = 0; j < 8; j++) pa[j] = (short)f2bf(sc[kb][ss * 8 + j]);
          const int chunk = (kb * 2 + ss) * 2 + gp;
#pragma unroll
          for (int dt = 0; dt < 2; dt++) {
            const int row = dt * 32 + l31;
            bf16x8 bv = *(const bf16x8*)&Vsh[row * 64 + ((chunk ^ (row & 7)) << 3)];
            o[dt] = __builtin_amdgcn_mfma_f32_32x32x16_bf16(pa, bv, o[dt], 0, 0, 0);
          }
        }
      __builtin_amdgcn_s_setprio(0);
    }
  }
#undef LOADR

  // ---- merge k-groups (pool reused; K/V dead) ----
  BAR();
  f32x4* comb = (f32x4*)pool;
  const int ci = (wq * 64 + lane) * 9;
  if (g == 0) {
#pragma unroll
    for (int dt = 0; dt < 2; dt++)
#pragma unroll
      for (int qq = 0; qq < 4; qq++)
        comb[ci + dt * 4 + qq] =
            (f32x4){o[dt][qq * 4 + 0], o[dt][qq * 4 + 1],
                    o[dt][qq * 4 + 2], o[dt][qq * 4 + 3]};
    comb[ci + 8] = (f32x4){m_s, l_s, 0.f, 0.f};
  }
  BAR();
  if (g == 1) {
    f32x4 ml = comb[ci + 8];
    const float m0 = ml[0], l0 = ml[1];
    const float M  = fmaxf(m0, m_s);
    float u0 = __builtin_amdgcn_exp2f((m0 - M) * CEXP);
    float u1 = __builtin_amdgcn_exp2f((m_s - M) * CEXP);
    const float inv = 1.0f / (l0 * u0 + l_s * u1);
    u0 *= inv; u1 *= inv;
    float u0r[16], u1r[16];
#pragma unroll
    for (int r = 0; r < 16; r++) {
      const int mapr = (r & 3) + 8 * (r >> 2) + 4 * gp;
      u0r[r] = __shfl(u0, mapr, 64);
      u1r[r] = __shfl(u1, mapr, 64);
    }
#pragma unroll
    for (int dt = 0; dt < 2; dt++)
#pragma unroll
      for (int r = 0; r < 16; r++) {
        const float o0v = comb[ci + dt * 4 + (r >> 2)][r & 3];
        const float val = o0v * u0r[r] + o[dt][r] * u1r[r];
        const int rowg = qt * 128 + wq * 32 + (r & 3) + 8 * (r >> 2) + 4 * gp;
        Aout[(((size_t)(b * SEQ + rowg)) << 10) + h * 64 + dt * 32 + l31] = f2bf(val);
      }
  }
}

// ---------------- out projection: f32 out = Ab @ Wo^T + bo -------------------
// 128x64 tile, BK=64, async dbuf (48 KB -> 3 blocks/CU), vmcnt(6).
__global__ __launch_bounds__(256) void oproj_kernel(
    const u16* __restrict__ X, const u16* __restrict__ W,
    const float* __restrict__ bias, float* __restrict__ Out) {
  __shared__ u16 As[2][128 * 64];
  __shared__ u16 Bs[2][64 * 64];

  const int tid  = threadIdx.x;
  const int lane = tid & 63;
  const int wid  = tid >> 6;
  const int wm   = wid >> 1, wn = wid & 1;
  const int l15  = lane & 15;
  const int lhi  = lane >> 4;
  const int bm   = blockIdx.x * 128;
  const int bn   = blockIdx.y * 64;

  f32x4 acc[4][2];
#pragma unroll
  for (int i = 0; i < 4; i++)
#pragma unroll
    for (int j = 0; j < 2; j++) acc[i][j] = (f32x4){0.f, 0.f, 0.f, 0.f};

  const int lrow  = lane >> 3;
  const int gcol8 = lane & 7;

#define OPROJ_STAGE(buf, k0)                                                      \
  {                                                                               \
    _Pragma("unroll")                                                             \
    for (int c = 0; c < 4; c++) {                                                 \
      const int row  = c * 32 + wid * 8 + lrow;                                   \
      const int scol = (gcol8 ^ (row & 7)) * 8;                                   \
      gll16(X + (size_t)(bm + row) * HID + (k0) + scol,                           \
            (char*)&As[buf][0] + c * 4096 + wid * 1024);                          \
      if (c < 2)                                                                  \
        gll16(W + (size_t)(bn + row) * HID + (k0) + scol,                         \
              (char*)&Bs[buf][0] + c * 4096 + wid * 1024);                        \
    }                                                                             \
  }

  OPROJ_STAGE(0, 0);
  for (int t = 0; t < 16; t++) {
    BAR();
    if (t < 15) {
      OPROJ_STAGE((t + 1) & 1, (t + 1) * 64);
      asm volatile("s_waitcnt vmcnt(6)" ::: "memory");
    } else {
      asm volatile("s_waitcnt vmcnt(0)" ::: "memory");
    }
    BAR();
    SCHED0();
    const u16* A = &As[t & 1][0];
    const u16* B = &Bs[t & 1][0];
#pragma unroll
    for (int ks = 0; ks < 2; ks++) {
      bf16x8 af[4], bfm[2];
#pragma unroll
      for (int i = 0; i < 4; i++) {
        const int row = wm * 64 + i * 16 + l15;
        af[i] = *(const bf16x8*)&A[row * 64 + swz(row, ks * 32 + lhi * 8)];
      }
#pragma unroll
      for (int j = 0; j < 2; j++) {
        const int row = wn * 32 + j * 16 + l15;
        bfm[j] = *(const bf16x8*)&B[row * 64 + swz(row, ks * 32 + lhi * 8)];
      }
#pragma unroll
      for (int i = 0; i < 4; i++)
#pragma unroll
        for (int j = 0; j < 2; j++)
          acc[i][j] = __builtin_amdgcn_mfma_f32_16x16x32_bf16(af[i], bfm[j], acc[i][j], 0, 0, 0);
    }
  }
#undef OPROJ_STAGE

#pragma unroll
  for (int j = 0; j < 2; j++) {
    const int n = bn + wn * 32 + j * 16 + l15;
    const float bv_ = bias[n];
#pragma unroll
    for (int i = 0; i < 4; i++)
#pragma unroll
      for (int r = 0; r < 4; r++) {
        const int m = bm + wm * 64 + i * 16 + lhi * 4 + r;
        Out[(size_t)m * HID + n] = acc[i][j][r] + bv_;
      }
  }
}

// ---------------- launch ------------------------------------------------------
extern "C" void kernel_launch(void* const* d_in, const int* in_sizes, int n_in,
                              void* d_out, int out_size, void* d_ws, size_t ws_size,
                              hipStream_t stream) {
  const float* q  = (const float*)d_in[0];
  const float* k  = (const float*)d_in[1];
  const float* v  = (const float*)d_in[2];
  const float* Wq = (const float*)d_in[3];
  const float* bq = (const float*)d_in[4];
  const float* Wk = (const float*)d_in[5];
  const float* bk = (const float*)d_in[6];
  const float* Wv = (const float*)d_in[7];
  const float* bv = (const float*)d_in[8];
  const float* Wo = (const float*)d_in[9];
  const float* bo = (const float*)d_in[10];

  u16* ws   = (u16*)d_ws;
  u16* wqkv = ws;                     // Wq,Wk,Wv bf16 @ 0,1M,2M
  u16* wob  = ws + 3u * MEG;          // Wo bf16
  u16* qb   = ws + 4u * MEG;          // q bf16; reused as Ab after proj
  u16* Qb   = ws + 8u * MEG;          // [B,H,S,D]
  u16* Kb   = ws + 12u * MEG;         // [B,H,S,D]
  u16* Vtb  = ws + 16u * MEG;         // [B,H,D,S]
  u16* Ab   = qb;
  u16* kbf  = (u16*)d_out;            // k bf16 in d_out scratch
  u16* vbf  = (u16*)d_out + 4u * MEG; // v bf16

  cvt_kernel<<<dim3(1024, 16), 256, 0, stream>>>(Wq, Wk, Wv, Wo, q, k, v, ws, kbf);

  proj_kernel<<<dim3(32, 16, 3), 256, 0, stream>>>(qb, kbf, vbf, wqkv, bq, bk, bv,
                                                   Qb, Kb, Vtb);

  attn_kernel<<<dim3(512), 512, 0, stream>>>(Qb, Kb, Vtb, Ab);

  oproj_kernel<<<dim3(32, 16), 256, 0, stream>>>(Ab, wob, bo, (float*)d_out);
}